// Round 17
// baseline (138.854 us; speedup 1.0000x reference)
//
#include <hip/hip_runtime.h>

// ---------------- problem constants ----------------
#define MAX_IN   1024
#define MAX_OUT  4096
#define LOW_RANK 64
#define N_ARCH   16
#define HYP_HID  128
#define BATCH_M  8192   // 4 * 2048

typedef __attribute__((ext_vector_type(8))) short short8;   // 8 x bf16
typedef __attribute__((ext_vector_type(4))) float f32x4;

// round-to-nearest-even fp32 -> bf16
__device__ __forceinline__ unsigned short f2bf(float f) {
  union { float f; unsigned int u; } c; c.f = f;
  unsigned int r = c.u + 0x7fffu + ((c.u >> 16) & 1u);
  return (unsigned short)(r >> 16);
}

__device__ __forceinline__ void gload16(const unsigned short* g, unsigned short* l) {
  __builtin_amdgcn_global_load_lds(
      (const __attribute__((address_space(1))) unsigned int*)(g),
      (__attribute__((address_space(3))) unsigned int*)(l), 16, 0, 0);
}
__device__ __forceinline__ void gload16f(const float* g, float* l) {
  __builtin_amdgcn_global_load_lds(
      (const __attribute__((address_space(1))) unsigned int*)(g),
      (__attribute__((address_space(3))) unsigned int*)(l), 16, 0, 0);
}

// ---------------- kernel 1: X fp32 -> bf16 (R1-proven) ----------------
__global__ __launch_bounds__(256) void convert_x(const float* __restrict__ in,
                                                 unsigned short* __restrict__ out) {
  size_t i = (size_t)blockIdx.x * 256 + threadIdx.x;
  float4 v = *(const float4*)(in + i * 4);
  ushort4 o;
  o.x = f2bf(v.x); o.y = f2bf(v.y); o.z = f2bf(v.z); o.w = f2bf(v.w);
  *(ushort4*)(out + i * 4) = o;
}

// ---------------- kernel 2: W-build via DMA-staged matvec ----------------
// 1024 blocks x 256 thr, 4 W-rows (= 256 left-rows = 131 KB hyp_w2) each.
// hyp_w2 streamed through LDS via global_load_lds (register-independent DMA;
// the GEMM-staging mechanism, untested on prep until now): 8 chunks x 16 KB,
// double-buffered, 4 gload16/thread/chunk, vmcnt(4) + barrier.
// LDS bank uniformity: phys 16B-chunk = logical ^ (row&7), applied as inverse
// swizzle on the GLOBAL source (linear gload_lds dest, rule #21); ds_read_b128
// then hits each bank-group with exactly 8 lanes (optimal for 1 KB/instr).
__global__ __launch_bounds__(256) void build_w4(
    const float* __restrict__ w1, const float* __restrict__ b1,
    const float* __restrict__ e,
    const float* __restrict__ hyp_w2, const float* __restrict__ hyp_b2,
    const float* __restrict__ base_w, const float* __restrict__ lrf,
    unsigned short* __restrict__ Wbf) {
  __shared__ float hs[HYP_HID];
  __shared__ float lefts[4 * LOW_RANK];
  __shared__ __align__(16) float stage[2][32 * HYP_HID];   // 2 x 16 KB
  const int tid = threadIdx.x;
  const int o0 = blockIdx.x * 4;
  const int row0 = blockIdx.x * 256;       // first left-row of this block

  if (tid < HYP_HID) {
    const float4* wr = (const float4*)(w1 + tid * N_ARCH);
    float s = b1[tid];
#pragma unroll
    for (int c = 0; c < 4; c++) {
      float4 wv = wr[c];
      float4 ev = *(const float4*)(e + c * 4);
      s += wv.x * ev.x + wv.y * ev.y + wv.z * ev.z + wv.w * ev.w;
    }
    hs[tid] = fmaxf(s, 0.0f);
  }
  __syncthreads();

  // ---- staging source (inverse-swizzled): thread covers LDS slots j*256+tid,
  // row-in-chunk = j*8 + (tid>>5), phys chunk = tid&31,
  // logical chunk lc = (tid&31) ^ ((tid>>5)&7)   (j*8 doesn't affect row&7)
  const int rin = tid >> 5;                // row offset within 8-row group
  const int lc = (tid & 31) ^ (rin & 7);
  const float* srcT = hyp_w2 + ((size_t)row0 + rin) * HYP_HID + lc * 4;

#define STAGE(c)                                                               \
  do {                                                                         \
    float* dst = &stage[(c) & 1][0];                                           \
    _Pragma("unroll")                                                          \
    for (int j = 0; j < 4; j++)                                                \
      gload16f(srcT + (size_t)((c) * 32 + j * 8) * HYP_HID,                    \
               dst + (j * 256 + tid) * 4);                                     \
  } while (0)

  // ---- compute geometry: group g = tid>>3 handles row g of chunk; lane gl
  const int g = tid >> 3, gl = tid & 7;
  float4 hf[4];
#pragma unroll
  for (int j = 0; j < 4; j++) hf[j] = *(const float4*)(hs + gl * 16 + j * 4);
  // phys chunk for (row g, logical gl*4+j) = (gl*4+j) ^ (g&7)
  int rdoff[4];
#pragma unroll
  for (int j = 0; j < 4; j++)
    rdoff[4 - 1 - j] = g * HYP_HID + (((gl * 4 + j) ^ (g & 7)) * 4);
  // (order within j irrelevant for the sum; reversed to avoid aliasing warnings)

  STAGE(0);
  for (int c = 0; c < 8; ++c) {
    if (c + 1 < 8) {
      STAGE(c + 1);
      asm volatile("s_waitcnt vmcnt(4)" ::: "memory");  // chunk c landed
    } else {
      asm volatile("s_waitcnt vmcnt(0)" ::: "memory");
    }
    __builtin_amdgcn_s_barrier();
    __builtin_amdgcn_sched_barrier(0);

    const float* buf = &stage[c & 1][0];
    float s = 0.f;
#pragma unroll
    for (int j = 0; j < 4; j++) {
      float4 v = *(const float4*)(buf + rdoff[j]);
      // hf index must match logical chunk of rdoff[j]: rdoff[4-1-j] built from j
      // -> recompute pairing explicitly below instead
      s += 0.f * v.x;  // placeholder avoided; real pairing done in unrolled form
    }
    // explicit unrolled pairing (logical chunk j pairs with hf[j]):
    {
      float4 v0 = *(const float4*)(buf + g * HYP_HID + (((gl * 4 + 0) ^ (g & 7)) * 4));
      float4 v1 = *(const float4*)(buf + g * HYP_HID + (((gl * 4 + 1) ^ (g & 7)) * 4));
      float4 v2 = *(const float4*)(buf + g * HYP_HID + (((gl * 4 + 2) ^ (g & 7)) * 4));
      float4 v3 = *(const float4*)(buf + g * HYP_HID + (((gl * 4 + 3) ^ (g & 7)) * 4));
      s = v0.x * hf[0].x + v0.y * hf[0].y + v0.z * hf[0].z + v0.w * hf[0].w
        + v1.x * hf[1].x + v1.y * hf[1].y + v1.z * hf[1].z + v1.w * hf[1].w
        + v2.x * hf[2].x + v2.y * hf[2].y + v2.z * hf[2].z + v2.w * hf[2].w
        + v3.x * hf[3].x + v3.y * hf[3].y + v3.z * hf[3].z + v3.w * hf[3].w;
    }
    s += __shfl_xor(s, 4);
    s += __shfl_xor(s, 2);
    s += __shfl_xor(s, 1);
    const int rl = c * 32 + g;
    if (gl == 0) lefts[rl] = s + hyp_b2[row0 + rl];
    __builtin_amdgcn_s_barrier();
    __builtin_amdgcn_sched_barrier(0);
  }
#undef STAGE
  __syncthreads();

  // ---- phase 2: thread owns k0=tid*4..+3, all 4 rows ----
  const int k0 = tid * 4;
  float4 acc[4];
#pragma unroll
  for (int oi = 0; oi < 4; oi++)
    acc[oi] = *(const float4*)(base_w + (size_t)(o0 + oi) * MAX_IN + k0);
#pragma unroll 8
  for (int r = 0; r < LOW_RANK; r++) {
    float4 lv = *(const float4*)(lrf + r * MAX_IN + k0);
#pragma unroll
    for (int oi = 0; oi < 4; oi++) {
      const float lw = lefts[oi * LOW_RANK + r];   // LDS broadcast
      acc[oi].x += lw * lv.x; acc[oi].y += lw * lv.y;
      acc[oi].z += lw * lv.z; acc[oi].w += lw * lv.w;
    }
  }
#pragma unroll
  for (int oi = 0; oi < 4; oi++) {
    ushort4 o;
    o.x = f2bf(acc[oi].x); o.y = f2bf(acc[oi].y);
    o.z = f2bf(acc[oi].z); o.w = f2bf(acc[oi].w);
    *(ushort4*)(Wbf + (size_t)(o0 + oi) * MAX_IN + k0) = o;
  }
}

// ---------------- kernel 3: pipelined GEMM (R12/R15-verified, ~82 us, 828 TF) ----------------
// 128x256 tile, BK=32, 4 waves (2M x 2N), wave-tile 64x128 (4x8 frags of 16x16x32).
// 3 LDS buffers (72 KB) -> 2 blocks/CU. Prefetch distance 2, counted vmcnt(6).
// XCD macro-map: 16bm x 8bn per XCD, bm-major (B-cycle 4 MB = L2-resident).
// 0-conflict swizzle via pre-swizzled GLOBAL source + linear gload_lds dest.
__global__ __launch_bounds__(256, 2) void gemm_kernel(
    const unsigned short* __restrict__ A,   // [M][K] bf16
    const unsigned short* __restrict__ B,   // [N][K] bf16 (= W)
    const float* __restrict__ bias,         // [N]
    float* __restrict__ C) {                // [M][N] fp32
  constexpr int K = MAX_IN;
  constexpr int N = MAX_OUT;
  constexpr int ABUF = 128 * 32;           // 4096 ushorts = 8 KB
  constexpr int BBUF = 256 * 32;           // 8192 ushorts = 16 KB
  constexpr int TBUF = ABUF + BBUF;        // 12288 ushorts
  constexpr int NT = K / 32;               // 32 K-tiles
  __shared__ __align__(16) unsigned short lds[3 * TBUF];  // 72 KB

  const int tid = threadIdx.x;
  const int lane = tid & 63;
  const int w = tid >> 6;
  const int wm = w >> 1, wn = w & 1;
  const int fl = lane & 15, hi = lane >> 4;

  const int orig = blockIdx.x;
  const int xcd = orig & 7;
  const int mj = orig >> 3;                     // 0..127
  const int bm = ((xcd >> 1) * 16 + (mj >> 3)) * 128;   // 64 M-tiles
  const int bn = ((xcd & 1) * 8 + (mj & 7)) * 256;      // 16 N-tiles

  // ---- staging coords: slot s holds element (r = s>>2, c = (s&3)^((s>>3)&3)) ----
  const int sA0 = w * 128 + lane;          // + 64*j, j=0..1
  const int rA = sA0 >> 2;
  const int cA = (sA0 & 3) ^ ((sA0 >> 3) & 3);
  const int sB0 = w * 256 + lane;          // + 64*j, j=0..3
  const int rB = sB0 >> 2;
  const int cB = (sB0 & 3) ^ ((sB0 >> 3) & 3);
  const unsigned short* Ag = A + (size_t)(bm + rA) * K + cA * 8;
  const unsigned short* Bg = B + (size_t)(bn + rB) * K + cB * 8;

  // ---- fragment read bases (ushort offsets inside a tile buffer) ----
  const int swz = hi ^ ((fl >> 1) & 3);
  const int abase = (wm * 32 + (fl >> 1)) * 64 + (fl & 1) * 32 + swz * 8;
  const int bbase = (wn * 64 + (fl >> 1)) * 64 + (fl & 1) * 32 + swz * 8;

  f32x4 acc[4][8];
#pragma unroll
  for (int m = 0; m < 4; m++)
#pragma unroll
    for (int n = 0; n < 8; n++) acc[m][n] = (f32x4){0.f, 0.f, 0.f, 0.f};

#define STAGE(p, t)                                                            \
  do {                                                                         \
    unsigned short* la_ = &lds[(p) * TBUF];                                    \
    unsigned short* lb_ = la_ + ABUF;                                          \
    _Pragma("unroll")                                                          \
    for (int j = 0; j < 2; j++)                                                \
      gload16(Ag + (size_t)(16 * j) * K + (t) * 32, &la_[(sA0 + 64 * j) * 8]); \
    _Pragma("unroll")                                                          \
    for (int j = 0; j < 4; j++)                                                \
      gload16(Bg + (size_t)(16 * j) * K + (t) * 32, &lb_[(sB0 + 64 * j) * 8]); \
  } while (0)

  STAGE(0, 0);
  STAGE(1, 1);
  asm volatile("s_waitcnt vmcnt(6)" ::: "memory");
  __builtin_amdgcn_s_barrier();
  __builtin_amdgcn_sched_barrier(0);

  int p = 0;
  for (int t = 0; t < NT; ++t) {
    if (t + 2 < NT) {
      const int pn = (p + 2 >= 3) ? p - 1 : p + 2;
      STAGE(pn, t + 2);
    }
    const unsigned short* la = &lds[p * TBUF];
    const unsigned short* lb = la + ABUF;
    short8 a[4], b[8];
#pragma unroll
    for (int m = 0; m < 4; m++) a[m] = *(const short8*)&la[abase + m * 512];
#pragma unroll
    for (int n = 0; n < 8; n++) b[n] = *(const short8*)&lb[bbase + n * 512];
    __builtin_amdgcn_s_setprio(1);
#pragma unroll
    for (int m = 0; m < 4; m++)
#pragma unroll
      for (int n = 0; n < 8; n++)
        acc[m][n] = __builtin_amdgcn_mfma_f32_16x16x32_bf16(a[m], b[n], acc[m][n], 0, 0, 0);
    __builtin_amdgcn_s_setprio(0);
    if (t + 2 < NT) {
      asm volatile("s_waitcnt vmcnt(6)" ::: "memory");   // tile t+1 landed
    } else if (t + 2 == NT) {
      asm volatile("s_waitcnt vmcnt(0)" ::: "memory");   // final tile landed
    }
    if (t + 1 < NT) {
      __builtin_amdgcn_s_barrier();
      __builtin_amdgcn_sched_barrier(0);
    }
    p = (p + 1 == 3) ? 0 : p + 1;
  }
#undef STAGE

  // ---- epilogue: C/D layout col=lane&15, row=(lane>>4)*4+j ----
  float bv[8];
#pragma unroll
  for (int n = 0; n < 8; n++) bv[n] = bias[bn + wn * 128 + n * 16 + fl];
#pragma unroll
  for (int m = 0; m < 4; m++) {
    const int gr0 = bm + wm * 64 + m * 16 + hi * 4;
#pragma unroll
    for (int n = 0; n < 8; n++) {
      const int gc = bn + wn * 128 + n * 16 + fl;
#pragma unroll
      for (int j = 0; j < 4; j++)
        C[(size_t)(gr0 + j) * N + gc] = acc[m][n][j] + bv[n];
    }
  }
}

// ---------------- launcher ----------------
extern "C" void kernel_launch(void* const* d_in, const int* in_sizes, int n_in,
                              void* d_out, int out_size, void* d_ws, size_t ws_size,
                              hipStream_t stream) {
  const float* x      = (const float*)d_in[0];
  const float* embed  = (const float*)d_in[1];
  const float* base_w = (const float*)d_in[2];
  const float* base_b = (const float*)d_in[3];
  const float* lrf    = (const float*)d_in[4];
  const float* w1     = (const float*)d_in[5];
  const float* b1     = (const float*)d_in[6];
  const float* w2     = (const float*)d_in[7];
  const float* b2     = (const float*)d_in[8];
  float* out = (float*)d_out;

  char* ws = (char*)d_ws;
  unsigned short* Xbf = (unsigned short*)ws;                                   // 16 MB
  unsigned short* Wbf = (unsigned short*)(ws + (size_t)BATCH_M * MAX_IN * 2);  // 8 MB

  hipLaunchKernelGGL(convert_x, dim3(BATCH_M * MAX_IN / 1024), dim3(256), 0, stream, x, Xbf);
  hipLaunchKernelGGL(build_w4, dim3(MAX_OUT / 4), dim3(256), 0, stream,
                     w1, b1, embed, w2, b2, base_w, lrf, Wbf);
  hipLaunchKernelGGL(gemm_kernel, dim3((BATCH_M / 128) * (MAX_OUT / 256)), dim3(256), 0, stream,
                     Xbf, Wbf, base_b, out);
}

// Round 18
// 137.461 us; speedup vs baseline: 1.0101x; 1.0101x over previous
//
#include <hip/hip_runtime.h>

// ---------------- problem constants ----------------
#define MAX_IN   1024
#define MAX_OUT  4096
#define LOW_RANK 64
#define N_ARCH   16
#define HYP_HID  128
#define BATCH_M  8192   // 4 * 2048

typedef __attribute__((ext_vector_type(8))) short short8;   // 8 x bf16
typedef __attribute__((ext_vector_type(4))) float f32x4;

// round-to-nearest-even fp32 -> bf16
__device__ __forceinline__ unsigned short f2bf(float f) {
  union { float f; unsigned int u; } c; c.f = f;
  unsigned int r = c.u + 0x7fffu + ((c.u >> 16) & 1u);
  return (unsigned short)(r >> 16);
}

__device__ __forceinline__ void gload16(const unsigned short* g, unsigned short* l) {
  __builtin_amdgcn_global_load_lds(
      (const __attribute__((address_space(1))) unsigned int*)(g),
      (__attribute__((address_space(3))) unsigned int*)(l), 16, 0, 0);
}

// ---------------- kernel 1: X fp32 -> bf16 (R1-proven, ~8 us at copy BW) ----------------
__global__ __launch_bounds__(256) void convert_x(const float* __restrict__ in,
                                                 unsigned short* __restrict__ out) {
  size_t i = (size_t)blockIdx.x * 256 + threadIdx.x;
  float4 v = *(const float4*)(in + i * 4);
  ushort4 o;
  o.x = f2bf(v.x); o.y = f2bf(v.y); o.z = f2bf(v.z); o.w = f2bf(v.w);
  *(ushort4*)(out + i * 4) = o;
}

// ---------------- kernel 2: W-build, 4 rows/block, 1024 blocks (R15-best) ----------------
// 1-KB-contiguous wave loads (2 rows/instr), width-32 shfl reduce, 4-deep
// named-buffer pipeline. Measured-equivalent to R16/R17 variants; simplest.
__global__ __launch_bounds__(256) void build_w4(
    const float* __restrict__ w1, const float* __restrict__ b1,
    const float* __restrict__ e,
    const float* __restrict__ hyp_w2, const float* __restrict__ hyp_b2,
    const float* __restrict__ base_w, const float* __restrict__ lrf,
    unsigned short* __restrict__ Wbf) {
  __shared__ float hs[HYP_HID];
  __shared__ float lefts[4 * LOW_RANK];
  const int tid = threadIdx.x;
  const int o0 = blockIdx.x * 4;
  const int row0 = blockIdx.x * 256;       // first left-row of this block

  if (tid < HYP_HID) {
    const float4* wr = (const float4*)(w1 + tid * N_ARCH);
    float s = b1[tid];
#pragma unroll
    for (int c = 0; c < 4; c++) {
      float4 wv = wr[c];
      float4 ev = *(const float4*)(e + c * 4);
      s += wv.x * ev.x + wv.y * ev.y + wv.z * ev.z + wv.w * ev.w;
    }
    hs[tid] = fmaxf(s, 0.0f);
  }
  __syncthreads();

  const int lane = tid & 63;
  const int w = tid >> 6;
  const int half = lane >> 5;      // 0: even row of pair, 1: odd row
  const int sub = lane & 31;       // position within row (float4 index)
  const float4 hf = *(const float4*)(hs + sub * 4);

  // wave w covers left-rows [w*64, w*64+64) as 32 pairs; 1 KB contiguous/instr
  const float* src = hyp_w2 + ((size_t)row0 + w * 64 + half) * HYP_HID + sub * 4;

#define LDJ(j) (*(const float4*)(src + (size_t)(j) * 2 * HYP_HID))
#define PROC(v, j)                                                             \
  do {                                                                         \
    float s = v.x * hf.x + v.y * hf.y + v.z * hf.z + v.w * hf.w;               \
    s += __shfl_xor(s, 16);                                                    \
    s += __shfl_xor(s, 8);                                                     \
    s += __shfl_xor(s, 4);                                                     \
    s += __shfl_xor(s, 2);                                                     \
    s += __shfl_xor(s, 1);                                                     \
    const int rl_ = w * 64 + 2 * (j) + half;                                   \
    if (sub == 0) lefts[rl_] = s + hyp_b2[row0 + rl_];                         \
  } while (0)

  float4 v0 = LDJ(0), v1 = LDJ(1), v2 = LDJ(2), v3 = LDJ(3);
#pragma unroll
  for (int jj = 0; jj < 7; jj++) {
    PROC(v0, jj * 4 + 0); v0 = LDJ(jj * 4 + 4);
    PROC(v1, jj * 4 + 1); v1 = LDJ(jj * 4 + 5);
    PROC(v2, jj * 4 + 2); v2 = LDJ(jj * 4 + 6);
    PROC(v3, jj * 4 + 3); v3 = LDJ(jj * 4 + 7);
  }
  PROC(v0, 28); PROC(v1, 29); PROC(v2, 30); PROC(v3, 31);
#undef LDJ
#undef PROC
  __syncthreads();

  // ---- phase 2: thread owns k0=tid*4..+3, all 4 rows ----
  const int k0 = tid * 4;
  float4 acc[4];
#pragma unroll
  for (int oi = 0; oi < 4; oi++)
    acc[oi] = *(const float4*)(base_w + (size_t)(o0 + oi) * MAX_IN + k0);
#pragma unroll 8
  for (int r = 0; r < LOW_RANK; r++) {
    float4 lv = *(const float4*)(lrf + r * MAX_IN + k0);
#pragma unroll
    for (int oi = 0; oi < 4; oi++) {
      const float lw = lefts[oi * LOW_RANK + r];   // LDS broadcast
      acc[oi].x += lw * lv.x; acc[oi].y += lw * lv.y;
      acc[oi].z += lw * lv.z; acc[oi].w += lw * lv.w;
    }
  }
#pragma unroll
  for (int oi = 0; oi < 4; oi++) {
    ushort4 o;
    o.x = f2bf(acc[oi].x); o.y = f2bf(acc[oi].y);
    o.z = f2bf(acc[oi].z); o.w = f2bf(acc[oi].w);
    *(ushort4*)(Wbf + (size_t)(o0 + oi) * MAX_IN + k0) = o;
  }
}

// ---------------- kernel 3: pipelined GEMM (R12/R15-verified, ~82 us, 828 TF) ----------------
// 128x256 tile, BK=32, 4 waves (2M x 2N), wave-tile 64x128 (4x8 frags of 16x16x32).
// 3 LDS buffers (72 KB) -> 2 blocks/CU. Prefetch distance 2, counted vmcnt(6).
// XCD macro-map: 16bm x 8bn per XCD, bm-major (B-cycle 4 MB = L2-resident).
// 0-conflict swizzle via pre-swizzled GLOBAL source + linear gload_lds dest.
// 97.6% of the m248 full-stack reference (848 TF) at K=1024.
__global__ __launch_bounds__(256, 2) void gemm_kernel(
    const unsigned short* __restrict__ A,   // [M][K] bf16
    const unsigned short* __restrict__ B,   // [N][K] bf16 (= W)
    const float* __restrict__ bias,         // [N]
    float* __restrict__ C) {                // [M][N] fp32
  constexpr int K = MAX_IN;
  constexpr int N = MAX_OUT;
  constexpr int ABUF = 128 * 32;           // 4096 ushorts = 8 KB
  constexpr int BBUF = 256 * 32;           // 8192 ushorts = 16 KB
  constexpr int TBUF = ABUF + BBUF;        // 12288 ushorts
  constexpr int NT = K / 32;               // 32 K-tiles
  __shared__ __align__(16) unsigned short lds[3 * TBUF];  // 72 KB

  const int tid = threadIdx.x;
  const int lane = tid & 63;
  const int w = tid >> 6;
  const int wm = w >> 1, wn = w & 1;
  const int fl = lane & 15, hi = lane >> 4;

  const int orig = blockIdx.x;
  const int xcd = orig & 7;
  const int mj = orig >> 3;                     // 0..127
  const int bm = ((xcd >> 1) * 16 + (mj >> 3)) * 128;   // 64 M-tiles
  const int bn = ((xcd & 1) * 8 + (mj & 7)) * 256;      // 16 N-tiles

  // ---- staging coords: slot s holds element (r = s>>2, c = (s&3)^((s>>3)&3)) ----
  const int sA0 = w * 128 + lane;          // + 64*j, j=0..1
  const int rA = sA0 >> 2;
  const int cA = (sA0 & 3) ^ ((sA0 >> 3) & 3);
  const int sB0 = w * 256 + lane;          // + 64*j, j=0..3
  const int rB = sB0 >> 2;
  const int cB = (sB0 & 3) ^ ((sB0 >> 3) & 3);
  const unsigned short* Ag = A + (size_t)(bm + rA) * K + cA * 8;
  const unsigned short* Bg = B + (size_t)(bn + rB) * K + cB * 8;

  // ---- fragment read bases (ushort offsets inside a tile buffer) ----
  const int swz = hi ^ ((fl >> 1) & 3);
  const int abase = (wm * 32 + (fl >> 1)) * 64 + (fl & 1) * 32 + swz * 8;
  const int bbase = (wn * 64 + (fl >> 1)) * 64 + (fl & 1) * 32 + swz * 8;

  f32x4 acc[4][8];
#pragma unroll
  for (int m = 0; m < 4; m++)
#pragma unroll
    for (int n = 0; n < 8; n++) acc[m][n] = (f32x4){0.f, 0.f, 0.f, 0.f};

#define STAGE(p, t)                                                            \
  do {                                                                         \
    unsigned short* la_ = &lds[(p) * TBUF];                                    \
    unsigned short* lb_ = la_ + ABUF;                                          \
    _Pragma("unroll")                                                          \
    for (int j = 0; j < 2; j++)                                                \
      gload16(Ag + (size_t)(16 * j) * K + (t) * 32, &la_[(sA0 + 64 * j) * 8]); \
    _Pragma("unroll")                                                          \
    for (int j = 0; j < 4; j++)                                                \
      gload16(Bg + (size_t)(16 * j) * K + (t) * 32, &lb_[(sB0 + 64 * j) * 8]); \
  } while (0)

  STAGE(0, 0);
  STAGE(1, 1);
  asm volatile("s_waitcnt vmcnt(6)" ::: "memory");
  __builtin_amdgcn_s_barrier();
  __builtin_amdgcn_sched_barrier(0);

  int p = 0;
  for (int t = 0; t < NT; ++t) {
    if (t + 2 < NT) {
      const int pn = (p + 2 >= 3) ? p - 1 : p + 2;
      STAGE(pn, t + 2);
    }
    const unsigned short* la = &lds[p * TBUF];
    const unsigned short* lb = la + ABUF;
    short8 a[4], b[8];
#pragma unroll
    for (int m = 0; m < 4; m++) a[m] = *(const short8*)&la[abase + m * 512];
#pragma unroll
    for (int n = 0; n < 8; n++) b[n] = *(const short8*)&lb[bbase + n * 512];
    __builtin_amdgcn_s_setprio(1);
#pragma unroll
    for (int m = 0; m < 4; m++)
#pragma unroll
      for (int n = 0; n < 8; n++)
        acc[m][n] = __builtin_amdgcn_mfma_f32_16x16x32_bf16(a[m], b[n], acc[m][n], 0, 0, 0);
    __builtin_amdgcn_s_setprio(0);
    if (t + 2 < NT) {
      asm volatile("s_waitcnt vmcnt(6)" ::: "memory");   // tile t+1 landed
    } else if (t + 2 == NT) {
      asm volatile("s_waitcnt vmcnt(0)" ::: "memory");   // final tile landed
    }
    if (t + 1 < NT) {
      __builtin_amdgcn_s_barrier();
      __builtin_amdgcn_sched_barrier(0);
    }
    p = (p + 1 == 3) ? 0 : p + 1;
  }
#undef STAGE

  // ---- epilogue: C/D layout col=lane&15, row=(lane>>4)*4+j ----
  float bv[8];
#pragma unroll
  for (int n = 0; n < 8; n++) bv[n] = bias[bn + wn * 128 + n * 16 + fl];
#pragma unroll
  for (int m = 0; m < 4; m++) {
    const int gr0 = bm + wm * 64 + m * 16 + hi * 4;
#pragma unroll
    for (int n = 0; n < 8; n++) {
      const int gc = bn + wn * 128 + n * 16 + fl;
#pragma unroll
      for (int j = 0; j < 4; j++)
        C[(size_t)(gr0 + j) * N + gc] = acc[m][n][j] + bv[n];
    }
  }
}

// ---------------- launcher ----------------
extern "C" void kernel_launch(void* const* d_in, const int* in_sizes, int n_in,
                              void* d_out, int out_size, void* d_ws, size_t ws_size,
                              hipStream_t stream) {
  const float* x      = (const float*)d_in[0];
  const float* embed  = (const float*)d_in[1];
  const float* base_w = (const float*)d_in[2];
  const float* base_b = (const float*)d_in[3];
  const float* lrf    = (const float*)d_in[4];
  const float* w1     = (const float*)d_in[5];
  const float* b1     = (const float*)d_in[6];
  const float* w2     = (const float*)d_in[7];
  const float* b2     = (const float*)d_in[8];
  float* out = (float*)d_out;

  char* ws = (char*)d_ws;
  unsigned short* Xbf = (unsigned short*)ws;                                   // 16 MB
  unsigned short* Wbf = (unsigned short*)(ws + (size_t)BATCH_M * MAX_IN * 2);  // 8 MB

  hipLaunchKernelGGL(convert_x, dim3(BATCH_M * MAX_IN / 1024), dim3(256), 0, stream, x, Xbf);
  hipLaunchKernelGGL(build_w4, dim3(MAX_OUT / 4), dim3(256), 0, stream,
                     w1, b1, embed, w2, b2, base_w, lrf, Wbf);
  hipLaunchKernelGGL(gemm_kernel, dim3((BATCH_M / 128) * (MAX_OUT / 256)), dim3(256), 0, stream,
                     Xbf, Wbf, base_b, out);
}

// Round 19
// 126.723 us; speedup vs baseline: 1.0957x; 1.0847x over previous
//
#include <hip/hip_runtime.h>

// ---------------- problem constants ----------------
#define MAX_IN   1024
#define MAX_OUT  4096
#define LOW_RANK 64
#define N_ARCH   16
#define HYP_HID  128
#define BATCH_M  8192   // 4 * 2048

typedef __attribute__((ext_vector_type(8))) short short8;   // 8 x bf16
typedef __attribute__((ext_vector_type(4))) float f32x4;

// round-to-nearest-even fp32 -> bf16
__device__ __forceinline__ unsigned short f2bf(float f) {
  union { float f; unsigned int u; } c; c.f = f;
  unsigned int r = c.u + 0x7fffu + ((c.u >> 16) & 1u);
  return (unsigned short)(r >> 16);
}

__device__ __forceinline__ void gload16(const unsigned short* g, unsigned short* l) {
  __builtin_amdgcn_global_load_lds(
      (const __attribute__((address_space(1))) unsigned int*)(g),
      (__attribute__((address_space(3))) unsigned int*)(l), 16, 0, 0);
}

// non-temporal 16B load (nt-flagged global_load_dwordx4): single-use streams
__device__ __forceinline__ f32x4 ntload4(const float* p) {
  return __builtin_nontemporal_load((const f32x4*)p);
}

// ---------------- kernel 1: X fp32 -> bf16 (R1-proven, ~8 us) ----------------
__global__ __launch_bounds__(256) void convert_x(const float* __restrict__ in,
                                                 unsigned short* __restrict__ out) {
  size_t i = (size_t)blockIdx.x * 256 + threadIdx.x;
  float4 v = *(const float4*)(in + i * 4);
  ushort4 o;
  o.x = f2bf(v.x); o.y = f2bf(v.y); o.z = f2bf(v.z); o.w = f2bf(v.w);
  *(ushort4*)(out + i * 4) = o;
}

// ---------------- kernel 2: W-build, 4 rows/block, 1024 blocks ----------------
// R15 structure + NON-TEMPORAL loads on the single-use streams (hyp_w2,
// base_w). Cache-path experiment: if the ~3 TB/s wall is the L3-hit service
// path, nt loads bypass it. lrf stays cached (reused by all blocks).
__global__ __launch_bounds__(256) void build_w4(
    const float* __restrict__ w1, const float* __restrict__ b1,
    const float* __restrict__ e,
    const float* __restrict__ hyp_w2, const float* __restrict__ hyp_b2,
    const float* __restrict__ base_w, const float* __restrict__ lrf,
    unsigned short* __restrict__ Wbf) {
  __shared__ float hs[HYP_HID];
  __shared__ float lefts[4 * LOW_RANK];
  const int tid = threadIdx.x;
  const int o0 = blockIdx.x * 4;
  const int row0 = blockIdx.x * 256;       // first left-row of this block

  if (tid < HYP_HID) {
    const float4* wr = (const float4*)(w1 + tid * N_ARCH);
    float s = b1[tid];
#pragma unroll
    for (int c = 0; c < 4; c++) {
      float4 wv = wr[c];
      float4 ev = *(const float4*)(e + c * 4);
      s += wv.x * ev.x + wv.y * ev.y + wv.z * ev.z + wv.w * ev.w;
    }
    hs[tid] = fmaxf(s, 0.0f);
  }
  __syncthreads();

  const int lane = tid & 63;
  const int w = tid >> 6;
  const int half = lane >> 5;      // 0: even row of pair, 1: odd row
  const int sub = lane & 31;       // position within row (float4 index)
  const float4 hfv = *(const float4*)(hs + sub * 4);

  // wave w covers left-rows [w*64, w*64+64) as 32 pairs; 1 KB contiguous/instr
  const float* src = hyp_w2 + ((size_t)row0 + w * 64 + half) * HYP_HID + sub * 4;

#define LDJ(j) ntload4(src + (size_t)(j) * 2 * HYP_HID)
#define PROC(v, j)                                                             \
  do {                                                                         \
    float s = v.x * hfv.x + v.y * hfv.y + v.z * hfv.z + v.w * hfv.w;           \
    s += __shfl_xor(s, 16);                                                    \
    s += __shfl_xor(s, 8);                                                     \
    s += __shfl_xor(s, 4);                                                     \
    s += __shfl_xor(s, 2);                                                     \
    s += __shfl_xor(s, 1);                                                     \
    const int rl_ = w * 64 + 2 * (j) + half;                                   \
    if (sub == 0) lefts[rl_] = s + hyp_b2[row0 + rl_];                         \
  } while (0)

  f32x4 v0 = LDJ(0), v1 = LDJ(1), v2 = LDJ(2), v3 = LDJ(3);
#pragma unroll
  for (int jj = 0; jj < 7; jj++) {
    PROC(v0, jj * 4 + 0); v0 = LDJ(jj * 4 + 4);
    PROC(v1, jj * 4 + 1); v1 = LDJ(jj * 4 + 5);
    PROC(v2, jj * 4 + 2); v2 = LDJ(jj * 4 + 6);
    PROC(v3, jj * 4 + 3); v3 = LDJ(jj * 4 + 7);
  }
  PROC(v0, 28); PROC(v1, 29); PROC(v2, 30); PROC(v3, 31);
#undef LDJ
#undef PROC
  __syncthreads();

  // ---- phase 2: thread owns k0=tid*4..+3, all 4 rows ----
  const int k0 = tid * 4;
  f32x4 acc[4];
#pragma unroll
  for (int oi = 0; oi < 4; oi++)
    acc[oi] = ntload4(base_w + (size_t)(o0 + oi) * MAX_IN + k0);   // single-use
#pragma unroll 8
  for (int r = 0; r < LOW_RANK; r++) {
    float4 lv = *(const float4*)(lrf + r * MAX_IN + k0);           // reused -> cached
#pragma unroll
    for (int oi = 0; oi < 4; oi++) {
      const float lw = lefts[oi * LOW_RANK + r];   // LDS broadcast
      acc[oi].x += lw * lv.x; acc[oi].y += lw * lv.y;
      acc[oi].z += lw * lv.z; acc[oi].w += lw * lv.w;
    }
  }
#pragma unroll
  for (int oi = 0; oi < 4; oi++) {
    ushort4 o;
    o.x = f2bf(acc[oi].x); o.y = f2bf(acc[oi].y);
    o.z = f2bf(acc[oi].z); o.w = f2bf(acc[oi].w);
    *(ushort4*)(Wbf + (size_t)(o0 + oi) * MAX_IN + k0) = o;
  }
}

// ---------------- kernel 3: pipelined GEMM (R12/R18-verified, ~81 us, 846 TF) ----------------
// 128x256 tile, BK=32, 4 waves (2M x 2N), wave-tile 64x128 (4x8 frags of 16x16x32).
// 3 LDS buffers (72 KB) -> 2 blocks/CU. Prefetch distance 2, counted vmcnt(6).
// XCD macro-map: 16bm x 8bn per XCD, bm-major (B-cycle 4 MB = L2-resident).
// 0-conflict swizzle via pre-swizzled GLOBAL source + linear gload_lds dest.
// 99.8% of the m248 full-stack reference (848 TF) at K=1024.
__global__ __launch_bounds__(256, 2) void gemm_kernel(
    const unsigned short* __restrict__ A,   // [M][K] bf16
    const unsigned short* __restrict__ B,   // [N][K] bf16 (= W)
    const float* __restrict__ bias,         // [N]
    float* __restrict__ C) {                // [M][N] fp32
  constexpr int K = MAX_IN;
  constexpr int N = MAX_OUT;
  constexpr int ABUF = 128 * 32;           // 4096 ushorts = 8 KB
  constexpr int BBUF = 256 * 32;           // 8192 ushorts = 16 KB
  constexpr int TBUF = ABUF + BBUF;        // 12288 ushorts
  constexpr int NT = K / 32;               // 32 K-tiles
  __shared__ __align__(16) unsigned short lds[3 * TBUF];  // 72 KB

  const int tid = threadIdx.x;
  const int lane = tid & 63;
  const int w = tid >> 6;
  const int wm = w >> 1, wn = w & 1;
  const int fl = lane & 15, hi = lane >> 4;

  const int orig = blockIdx.x;
  const int xcd = orig & 7;
  const int mj = orig >> 3;                     // 0..127
  const int bm = ((xcd >> 1) * 16 + (mj >> 3)) * 128;   // 64 M-tiles
  const int bn = ((xcd & 1) * 8 + (mj & 7)) * 256;      // 16 N-tiles

  // ---- staging coords: slot s holds element (r = s>>2, c = (s&3)^((s>>3)&3)) ----
  const int sA0 = w * 128 + lane;          // + 64*j, j=0..1
  const int rA = sA0 >> 2;
  const int cA = (sA0 & 3) ^ ((sA0 >> 3) & 3);
  const int sB0 = w * 256 + lane;          // + 64*j, j=0..3
  const int rB = sB0 >> 2;
  const int cB = (sB0 & 3) ^ ((sB0 >> 3) & 3);
  const unsigned short* Ag = A + (size_t)(bm + rA) * K + cA * 8;
  const unsigned short* Bg = B + (size_t)(bn + rB) * K + cB * 8;

  // ---- fragment read bases (ushort offsets inside a tile buffer) ----
  const int swz = hi ^ ((fl >> 1) & 3);
  const int abase = (wm * 32 + (fl >> 1)) * 64 + (fl & 1) * 32 + swz * 8;
  const int bbase = (wn * 64 + (fl >> 1)) * 64 + (fl & 1) * 32 + swz * 8;

  f32x4 acc[4][8];
#pragma unroll
  for (int m = 0; m < 4; m++)
#pragma unroll
    for (int n = 0; n < 8; n++) acc[m][n] = (f32x4){0.f, 0.f, 0.f, 0.f};

#define STAGE(p, t)                                                            \
  do {                                                                         \
    unsigned short* la_ = &lds[(p) * TBUF];                                    \
    unsigned short* lb_ = la_ + ABUF;                                          \
    _Pragma("unroll")                                                          \
    for (int j = 0; j < 2; j++)                                                \
      gload16(Ag + (size_t)(16 * j) * K + (t) * 32, &la_[(sA0 + 64 * j) * 8]); \
    _Pragma("unroll")                                                          \
    for (int j = 0; j < 4; j++)                                                \
      gload16(Bg + (size_t)(16 * j) * K + (t) * 32, &lb_[(sB0 + 64 * j) * 8]); \
  } while (0)

  STAGE(0, 0);
  STAGE(1, 1);
  asm volatile("s_waitcnt vmcnt(6)" ::: "memory");
  __builtin_amdgcn_s_barrier();
  __builtin_amdgcn_sched_barrier(0);

  int p = 0;
  for (int t = 0; t < NT; ++t) {
    if (t + 2 < NT) {
      const int pn = (p + 2 >= 3) ? p - 1 : p + 2;
      STAGE(pn, t + 2);
    }
    const unsigned short* la = &lds[p * TBUF];
    const unsigned short* lb = la + ABUF;
    short8 a[4], b[8];
#pragma unroll
    for (int m = 0; m < 4; m++) a[m] = *(const short8*)&la[abase + m * 512];
#pragma unroll
    for (int n = 0; n < 8; n++) b[n] = *(const short8*)&lb[bbase + n * 512];
    __builtin_amdgcn_s_setprio(1);
#pragma unroll
    for (int m = 0; m < 4; m++)
#pragma unroll
      for (int n = 0; n < 8; n++)
        acc[m][n] = __builtin_amdgcn_mfma_f32_16x16x32_bf16(a[m], b[n], acc[m][n], 0, 0, 0);
    __builtin_amdgcn_s_setprio(0);
    if (t + 2 < NT) {
      asm volatile("s_waitcnt vmcnt(6)" ::: "memory");   // tile t+1 landed
    } else if (t + 2 == NT) {
      asm volatile("s_waitcnt vmcnt(0)" ::: "memory");   // final tile landed
    }
    if (t + 1 < NT) {
      __builtin_amdgcn_s_barrier();
      __builtin_amdgcn_sched_barrier(0);
    }
    p = (p + 1 == 3) ? 0 : p + 1;
  }
#undef STAGE

  // ---- epilogue: C/D layout col=lane&15, row=(lane>>4)*4+j ----
  float bv[8];
#pragma unroll
  for (int n = 0; n < 8; n++) bv[n] = bias[bn + wn * 128 + n * 16 + fl];
#pragma unroll
  for (int m = 0; m < 4; m++) {
    const int gr0 = bm + wm * 64 + m * 16 + hi * 4;
#pragma unroll
    for (int n = 0; n < 8; n++) {
      const int gc = bn + wn * 128 + n * 16 + fl;
#pragma unroll
      for (int j = 0; j < 4; j++)
        C[(size_t)(gr0 + j) * N + gc] = acc[m][n][j] + bv[n];
    }
  }
}

// ---------------- launcher ----------------
extern "C" void kernel_launch(void* const* d_in, const int* in_sizes, int n_in,
                              void* d_out, int out_size, void* d_ws, size_t ws_size,
                              hipStream_t stream) {
  const float* x      = (const float*)d_in[0];
  const float* embed  = (const float*)d_in[1];
  const float* base_w = (const float*)d_in[2];
  const float* base_b = (const float*)d_in[3];
  const float* lrf    = (const float*)d_in[4];
  const float* w1     = (const float*)d_in[5];
  const float* b1     = (const float*)d_in[6];
  const float* w2     = (const float*)d_in[7];
  const float* b2     = (const float*)d_in[8];
  float* out = (float*)d_out;

  char* ws = (char*)d_ws;
  unsigned short* Xbf = (unsigned short*)ws;                                   // 16 MB
  unsigned short* Wbf = (unsigned short*)(ws + (size_t)BATCH_M * MAX_IN * 2);  // 8 MB

  hipLaunchKernelGGL(convert_x, dim3(BATCH_M * MAX_IN / 1024), dim3(256), 0, stream, x, Xbf);
  hipLaunchKernelGGL(build_w4, dim3(MAX_OUT / 4), dim3(256), 0, stream,
                     w1, b1, embed, w2, b2, base_w, lrf, Wbf);
  hipLaunchKernelGGL(gemm_kernel, dim3((BATCH_M / 128) * (MAX_OUT / 256)), dim3(256), 0, stream,
                     Xbf, Wbf, base_b, out);
}